// Round 4
// baseline (131.255 us; speedup 1.0000x reference)
//
#include <hip/hip_runtime.h>
#include <hip/hip_cooperative_groups.h>

namespace cg = cooperative_groups;

// FK loss: B=262144, 7-DOF DH chain -> (pos, rpy) -> MSE vs poses.
// R4: single cooperative kernel (fused reduce via grid.sync), float4
//     LDS-staged inputs, fast HW trig + branchless atan2.

#define FK_B 262144
#define NBLK (FK_B / 256)   // 1024 blocks

// Branchless atan2, Cephes-style. Max error ~1e-7 rad.
__device__ __forceinline__ float fast_atan2f(float y, float x) {
    const float ax = fabsf(x), ay = fabsf(y);
    const float mx = fmaxf(ax, ay);
    const float mn = fminf(ax, ay);
    float t = __fdividef(mn, fmaxf(mx, 1e-30f));
    const bool red = t > 0.41421356f;                  // tan(pi/8)
    const float tr = __fdividef(t - 1.0f, t + 1.0f);
    float u = red ? tr : t;
    const float s = u * u;
    float p = fmaf(s, 8.05374449538e-2f, -1.38776856032e-1f);
    p = fmaf(s, p, 1.99777106478e-1f);
    p = fmaf(s, p, -3.33329491539e-1f);
    float r = fmaf(u * s, p, u);
    if (red) r += 0.78539816340f;
    if (ay > ax) r = 1.57079632679f - r;
    if (x < 0.0f) r = 3.14159265359f - r;
    return copysignf(r, y);
}

// T <- T * A(ct, st, d, a, cal, sal); bottom row [0,0,0,1].
__device__ __forceinline__ void dh_step(float R[3][3], float p[3],
                                        float ct, float st,
                                        float d, float a,
                                        float cal, float sal) {
    const float c0x = ct,        c0y = st,        c0z = 0.0f;
    const float c1x = -st * cal, c1y = ct * cal,  c1z = sal;
    const float c2x = st * sal,  c2y = -ct * sal, c2z = cal;
    const float px = a * ct, py = a * st, pz = d;

    float nR[3][3], np[3];
#pragma unroll
    for (int r = 0; r < 3; ++r) {
        nR[r][0] = R[r][0] * c0x + R[r][1] * c0y + R[r][2] * c0z;
        nR[r][1] = R[r][0] * c1x + R[r][1] * c1y + R[r][2] * c1z;
        nR[r][2] = R[r][0] * c2x + R[r][1] * c2y + R[r][2] * c2z;
        np[r]    = R[r][0] * px  + R[r][1] * py  + R[r][2] * pz + p[r];
    }
#pragma unroll
    for (int r = 0; r < 3; ++r) {
        R[r][0] = nR[r][0]; R[r][1] = nR[r][1]; R[r][2] = nR[r][2];
        p[r] = np[r];
    }
}

__global__ __launch_bounds__(256) void fk_loss_fused(
    const float* __restrict__ joints,   // (B,7)
    const float* __restrict__ poses,    // (B,6)
    float* __restrict__ partials,       // (NBLK,) in d_ws
    float* __restrict__ out)            // scalar
{
    const int t   = threadIdx.x;
    const int bid = blockIdx.x;

    // --- Stage inputs to LDS with coalesced float4 loads ---
    __shared__ float4 j4[448];   // 256*7 floats
    __shared__ float4 p4[384];   // 256*6 floats
    const float4* jg = (const float4*)joints + bid * 448;
    const float4* pg = (const float4*)poses  + bid * 384;
    for (int k = t; k < 448; k += 256) j4[k] = jg[k];
    for (int k = t; k < 384; k += 256) p4[k] = pg[k];
    __syncthreads();
    const float* j_lds = (const float*)j4;
    const float* p_lds = (const float*)p4;

    float s[7], c[7];
#pragma unroll
    for (int k = 0; k < 7; ++k) {
        const float q = j_lds[t * 7 + k];
        s[k] = __sinf(q);
        c[k] = __cosf(q);
    }

    // T = A0: d=0.333, a=0, alpha=0
    float R[3][3] = {{c[0], -s[0], 0.0f},
                     {s[0],  c[0], 0.0f},
                     {0.0f,  0.0f, 1.0f}};
    float p[3] = {0.0f, 0.0f, 0.333f};

    //            ct    st     d       a        cal   sal
    dh_step(R, p, c[1], s[1], 0.0f,   0.0f,    0.0f, -1.0f);
    dh_step(R, p, c[2], s[2], 0.316f, 0.0f,    0.0f,  1.0f);
    dh_step(R, p, c[3], s[3], 0.0f,   0.0825f, 0.0f,  1.0f);
    dh_step(R, p, c[4], s[4], 0.384f,-0.0825f, 0.0f, -1.0f);
    dh_step(R, p, c[5], s[5], 0.0f,   0.0f,    0.0f,  1.0f);
    dh_step(R, p, c[6], s[6], 0.107f, 0.088f,  0.0f,  1.0f);

    float fk[6];
    fk[0] = p[0]; fk[1] = p[1]; fk[2] = p[2];
    fk[3] = fast_atan2f(-R[1][2], R[2][2]);
    const float r02 = fminf(1.0f, fmaxf(-1.0f, R[0][2]));
    fk[4] = fast_atan2f(r02, sqrtf(fmaxf(0.0f, 1.0f - r02 * r02)));
    fk[5] = fast_atan2f(-R[0][1], R[0][0]);

    float err = 0.0f;
#pragma unroll
    for (int k = 0; k < 6; ++k) {
        float dlt = fk[k] - p_lds[t * 6 + k];
        err += dlt * dlt;
    }

    // wave-64 reduction
#pragma unroll
    for (int off = 32; off > 0; off >>= 1)
        err += __shfl_down(err, off, 64);

    __shared__ float wsum[4];
    const int lane = t & 63;
    const int wid  = t >> 6;
    if (lane == 0) wsum[wid] = err;
    __syncthreads();
    if (t == 0) {
        partials[bid] = wsum[0] + wsum[1] + wsum[2] + wsum[3];
        __threadfence();
    }

    cg::this_grid().sync();

    // --- Final reduce: block 0 only ---
    if (bid == 0) {
        const float4* pp = (const float4*)partials;   // 256 float4 = 1024 floats
        const float4 v4 = pp[t];
        float v = (v4.x + v4.y) + (v4.z + v4.w);
#pragma unroll
        for (int off = 32; off > 0; off >>= 1)
            v += __shfl_down(v, off, 64);
        __shared__ float fsum[4];
        if (lane == 0) fsum[wid] = v;
        __syncthreads();
        if (t == 0)
            out[0] = (fsum[0] + fsum[1] + fsum[2] + fsum[3]) * (1.0f / (FK_B * 6.0f));
    }
}

extern "C" void kernel_launch(void* const* d_in, const int* in_sizes, int n_in,
                              void* d_out, int out_size, void* d_ws, size_t ws_size,
                              hipStream_t stream) {
    const float* joints = (const float*)d_in[0];
    const float* poses  = (const float*)d_in[1];
    float* out      = (float*)d_out;
    float* partials = (float*)d_ws;

    void* args[] = {(void*)&joints, (void*)&poses, (void*)&partials, (void*)&out};
    hipLaunchCooperativeKernel((const void*)fk_loss_fused,
                               dim3(NBLK), dim3(256), args, 0, stream);
}

// Round 5
// 78.014 us; speedup vs baseline: 1.6825x; 1.6825x over previous
//
#include <hip/hip_runtime.h>

// FK loss: B=262144, 7-DOF DH chain -> (pos, rpy) -> MSE vs poses.
// R5: single plain dispatch. LDS float4-staged inputs, HW trig, branchless
//     atan2, block reduce -> one f32 atomicAdd per block (scaled).
//     d_out zeroed via 4-byte hipMemsetAsync (graph-capture safe).

#define FK_B 262144
#define NBLK (FK_B / 256)   // 1024 blocks

// Branchless atan2, Cephes-style. Max error ~1e-7 rad.
__device__ __forceinline__ float fast_atan2f(float y, float x) {
    const float ax = fabsf(x), ay = fabsf(y);
    const float mx = fmaxf(ax, ay);
    const float mn = fminf(ax, ay);
    float t = __fdividef(mn, fmaxf(mx, 1e-30f));
    const bool red = t > 0.41421356f;                  // tan(pi/8)
    const float tr = __fdividef(t - 1.0f, t + 1.0f);
    float u = red ? tr : t;
    const float s = u * u;
    float p = fmaf(s, 8.05374449538e-2f, -1.38776856032e-1f);
    p = fmaf(s, p, 1.99777106478e-1f);
    p = fmaf(s, p, -3.33329491539e-1f);
    float r = fmaf(u * s, p, u);
    if (red) r += 0.78539816340f;
    if (ay > ax) r = 1.57079632679f - r;
    if (x < 0.0f) r = 3.14159265359f - r;
    return copysignf(r, y);
}

// T <- T * A(ct, st, d, a, cal, sal); bottom row [0,0,0,1].
__device__ __forceinline__ void dh_step(float R[3][3], float p[3],
                                        float ct, float st,
                                        float d, float a,
                                        float cal, float sal) {
    const float c0x = ct,        c0y = st,        c0z = 0.0f;
    const float c1x = -st * cal, c1y = ct * cal,  c1z = sal;
    const float c2x = st * sal,  c2y = -ct * sal, c2z = cal;
    const float px = a * ct, py = a * st, pz = d;

    float nR[3][3], np[3];
#pragma unroll
    for (int r = 0; r < 3; ++r) {
        nR[r][0] = R[r][0] * c0x + R[r][1] * c0y + R[r][2] * c0z;
        nR[r][1] = R[r][0] * c1x + R[r][1] * c1y + R[r][2] * c1z;
        nR[r][2] = R[r][0] * c2x + R[r][1] * c2y + R[r][2] * c2z;
        np[r]    = R[r][0] * px  + R[r][1] * py  + R[r][2] * pz + p[r];
    }
#pragma unroll
    for (int r = 0; r < 3; ++r) {
        R[r][0] = nR[r][0]; R[r][1] = nR[r][1]; R[r][2] = nR[r][2];
        p[r] = np[r];
    }
}

__global__ __launch_bounds__(256) void fk_loss_kernel(
    const float* __restrict__ joints,   // (B,7)
    const float* __restrict__ poses,    // (B,6)
    float* __restrict__ out)            // scalar, pre-zeroed
{
    const int t   = threadIdx.x;
    const int bid = blockIdx.x;

    // Coalesced float4 staging to LDS
    __shared__ float4 j4[448];   // 256*7 floats
    __shared__ float4 p4[384];   // 256*6 floats
    const float4* jg = (const float4*)joints + bid * 448;
    const float4* pg = (const float4*)poses  + bid * 384;
    for (int k = t; k < 448; k += 256) j4[k] = jg[k];
    for (int k = t; k < 384; k += 256) p4[k] = pg[k];
    __syncthreads();
    const float* j_lds = (const float*)j4;
    const float* p_lds = (const float*)p4;

    float s[7], c[7];
#pragma unroll
    for (int k = 0; k < 7; ++k) {
        const float q = j_lds[t * 7 + k];
        s[k] = __sinf(q);    // |q| ~ N(0,1): HW trig fully accurate
        c[k] = __cosf(q);
    }

    // T = A0: d=0.333, a=0, alpha=0
    float R[3][3] = {{c[0], -s[0], 0.0f},
                     {s[0],  c[0], 0.0f},
                     {0.0f,  0.0f, 1.0f}};
    float p[3] = {0.0f, 0.0f, 0.333f};

    //            ct    st     d       a        cal   sal
    dh_step(R, p, c[1], s[1], 0.0f,   0.0f,    0.0f, -1.0f);
    dh_step(R, p, c[2], s[2], 0.316f, 0.0f,    0.0f,  1.0f);
    dh_step(R, p, c[3], s[3], 0.0f,   0.0825f, 0.0f,  1.0f);
    dh_step(R, p, c[4], s[4], 0.384f,-0.0825f, 0.0f, -1.0f);
    dh_step(R, p, c[5], s[5], 0.0f,   0.0f,    0.0f,  1.0f);
    dh_step(R, p, c[6], s[6], 0.107f, 0.088f,  0.0f,  1.0f);

    float fk[6];
    fk[0] = p[0]; fk[1] = p[1]; fk[2] = p[2];
    fk[3] = fast_atan2f(-R[1][2], R[2][2]);
    const float r02 = fminf(1.0f, fmaxf(-1.0f, R[0][2]));
    fk[4] = fast_atan2f(r02, sqrtf(fmaxf(0.0f, 1.0f - r02 * r02)));
    fk[5] = fast_atan2f(-R[0][1], R[0][0]);

    float err = 0.0f;
#pragma unroll
    for (int k = 0; k < 6; ++k) {
        float dlt = fk[k] - p_lds[t * 6 + k];
        err += dlt * dlt;
    }

    // wave-64 reduction
#pragma unroll
    for (int off = 32; off > 0; off >>= 1)
        err += __shfl_down(err, off, 64);

    __shared__ float wsum[4];
    const int lane = t & 63;
    const int wid  = t >> 6;
    if (lane == 0) wsum[wid] = err;
    __syncthreads();
    if (t == 0) {
        const float v = wsum[0] + wsum[1] + wsum[2] + wsum[3];
        atomicAdd(out, v * (1.0f / (FK_B * 6.0f)));   // 1024 adds, L2-pipelined
    }
}

extern "C" void kernel_launch(void* const* d_in, const int* in_sizes, int n_in,
                              void* d_out, int out_size, void* d_ws, size_t ws_size,
                              hipStream_t stream) {
    const float* joints = (const float*)d_in[0];
    const float* poses  = (const float*)d_in[1];
    float* out = (float*)d_out;

    hipMemsetAsync(out, 0, sizeof(float), stream);  // d_out is poisoned 0xAA
    fk_loss_kernel<<<NBLK, 256, 0, stream>>>(joints, poses, out);
}

// Round 6
// 65.747 us; speedup vs baseline: 1.9964x; 1.1866x over previous
//
#include <hip/hip_runtime.h>

// FK loss: B=262144, 7-DOF DH chain -> (pos, rpy) -> MSE vs poses.
// R6: R3 structure (2 dispatches, partials in d_ws — no memset, no
//     same-address atomics) + ILP-2 (2 elements/thread, two independent
//     DH chains) + aligned float2 vector loads + single-wave reduce.

#define FK_B   262144
#define NBLK1  (FK_B / 512)   // 512 blocks, 256 thr, 2 elem/thread

// Branchless atan2, Cephes-style. Max error ~1e-7 rad.
__device__ __forceinline__ float fast_atan2f(float y, float x) {
    const float ax = fabsf(x), ay = fabsf(y);
    const float mx = fmaxf(ax, ay);
    const float mn = fminf(ax, ay);
    float t = __fdividef(mn, fmaxf(mx, 1e-30f));
    const bool red = t > 0.41421356f;                  // tan(pi/8)
    const float tr = __fdividef(t - 1.0f, t + 1.0f);
    float u = red ? tr : t;
    const float s = u * u;
    float p = fmaf(s, 8.05374449538e-2f, -1.38776856032e-1f);
    p = fmaf(s, p, 1.99777106478e-1f);
    p = fmaf(s, p, -3.33329491539e-1f);
    float r = fmaf(u * s, p, u);
    if (red) r += 0.78539816340f;
    if (ay > ax) r = 1.57079632679f - r;
    if (x < 0.0f) r = 3.14159265359f - r;
    return copysignf(r, y);
}

// T <- T * A(ct, st, d, a, cal, sal); bottom row [0,0,0,1].
__device__ __forceinline__ void dh_step(float R[3][3], float p[3],
                                        float ct, float st,
                                        float d, float a,
                                        float cal, float sal) {
    const float c0x = ct,        c0y = st,        c0z = 0.0f;
    const float c1x = -st * cal, c1y = ct * cal,  c1z = sal;
    const float c2x = st * sal,  c2y = -ct * sal, c2z = cal;
    const float px = a * ct, py = a * st, pz = d;

    float nR[3][3], np[3];
#pragma unroll
    for (int r = 0; r < 3; ++r) {
        nR[r][0] = R[r][0] * c0x + R[r][1] * c0y + R[r][2] * c0z;
        nR[r][1] = R[r][0] * c1x + R[r][1] * c1y + R[r][2] * c1z;
        nR[r][2] = R[r][0] * c2x + R[r][1] * c2y + R[r][2] * c2z;
        np[r]    = R[r][0] * px  + R[r][1] * py  + R[r][2] * pz + p[r];
    }
#pragma unroll
    for (int r = 0; r < 3; ++r) {
        R[r][0] = nR[r][0]; R[r][1] = nR[r][1]; R[r][2] = nR[r][2];
        p[r] = np[r];
    }
}

// One element's FK + squared error against its pose row (6 floats).
__device__ __forceinline__ float fk_err(const float* q7, const float* pose6) {
    float s[7], c[7];
#pragma unroll
    for (int k = 0; k < 7; ++k) {
        s[k] = __sinf(q7[k]);   // |q| ~ N(0,1): HW trig fully accurate
        c[k] = __cosf(q7[k]);
    }

    float R[3][3] = {{c[0], -s[0], 0.0f},
                     {s[0],  c[0], 0.0f},
                     {0.0f,  0.0f, 1.0f}};
    float p[3] = {0.0f, 0.0f, 0.333f};

    //            ct    st     d       a        cal   sal
    dh_step(R, p, c[1], s[1], 0.0f,   0.0f,    0.0f, -1.0f);
    dh_step(R, p, c[2], s[2], 0.316f, 0.0f,    0.0f,  1.0f);
    dh_step(R, p, c[3], s[3], 0.0f,   0.0825f, 0.0f,  1.0f);
    dh_step(R, p, c[4], s[4], 0.384f,-0.0825f, 0.0f, -1.0f);
    dh_step(R, p, c[5], s[5], 0.0f,   0.0f,    0.0f,  1.0f);
    dh_step(R, p, c[6], s[6], 0.107f, 0.088f,  0.0f,  1.0f);

    float fk[6];
    fk[0] = p[0]; fk[1] = p[1]; fk[2] = p[2];
    fk[3] = fast_atan2f(-R[1][2], R[2][2]);
    const float r02 = fminf(1.0f, fmaxf(-1.0f, R[0][2]));
    fk[4] = fast_atan2f(r02, sqrtf(fmaxf(0.0f, 1.0f - r02 * r02)));
    fk[5] = fast_atan2f(-R[0][1], R[0][0]);

    float err = 0.0f;
#pragma unroll
    for (int k = 0; k < 6; ++k) {
        const float d6 = fk[k] - pose6[k];
        err = fmaf(d6, d6, err);
    }
    return err;
}

__global__ __launch_bounds__(256) void fk_loss_kernel(
    const float* __restrict__ joints,   // (B,7)
    const float* __restrict__ poses,    // (B,6)
    float* __restrict__ partials)       // (NBLK1,)
{
    const int t = threadIdx.x;
    const int g = blockIdx.x * 256 + t;   // thread handles elements 2g, 2g+1

    // Dense aligned float2 loads: 14 joint floats + 12 pose floats.
    const float2* jg = (const float2*)joints + g * 7;
    const float2* pg = (const float2*)poses  + g * 6;

    float jq[14], pq[12];
#pragma unroll
    for (int k = 0; k < 7; ++k) {
        const float2 v = jg[k];
        jq[2 * k] = v.x; jq[2 * k + 1] = v.y;
    }
#pragma unroll
    for (int k = 0; k < 6; ++k) {
        const float2 v = pg[k];
        pq[2 * k] = v.x; pq[2 * k + 1] = v.y;
    }

    // Two independent DH chains (ILP-2).
    float err = fk_err(&jq[0], &pq[0]) + fk_err(&jq[7], &pq[6]);

    // wave-64 reduction
#pragma unroll
    for (int off = 32; off > 0; off >>= 1)
        err += __shfl_down(err, off, 64);

    __shared__ float wsum[4];
    const int lane = t & 63;
    const int wid  = t >> 6;
    if (lane == 0) wsum[wid] = err;
    __syncthreads();
    if (t == 0)
        partials[blockIdx.x] = wsum[0] + wsum[1] + wsum[2] + wsum[3];
}

// Single wave: 64 threads x 8 floats = 512 partials. No LDS, no barrier.
__global__ __launch_bounds__(64) void fk_reduce_kernel(
    const float* __restrict__ partials,  // (NBLK1,)
    float* __restrict__ out)             // scalar
{
    const int t = threadIdx.x;
    const float4* pp = (const float4*)partials;   // 128 float4
    const float4 a = pp[t];
    const float4 b = pp[t + 64];
    float v = ((a.x + a.y) + (a.z + a.w)) + ((b.x + b.y) + (b.z + b.w));

#pragma unroll
    for (int off = 32; off > 0; off >>= 1)
        v += __shfl_down(v, off, 64);

    if (t == 0)
        out[0] = v * (1.0f / (FK_B * 6.0f));
}

extern "C" void kernel_launch(void* const* d_in, const int* in_sizes, int n_in,
                              void* d_out, int out_size, void* d_ws, size_t ws_size,
                              hipStream_t stream) {
    const float* joints = (const float*)d_in[0];
    const float* poses  = (const float*)d_in[1];
    float* out      = (float*)d_out;
    float* partials = (float*)d_ws;   // poisoned each iter, fully overwritten

    fk_loss_kernel<<<NBLK1, 256, 0, stream>>>(joints, poses, partials);
    fk_reduce_kernel<<<1, 64, 0, stream>>>(partials, out);
}

// Round 7
// 65.627 us; speedup vs baseline: 2.0000x; 1.0018x over previous
//
#include <hip/hip_runtime.h>

// FK loss: B=262144, 7-DOF DH chain -> (pos, rpy) -> MSE vs poses.
// R7: SINGLE dispatch. Producers write per-wave partials as sentinel-encoded
//     device-scope atomic stores (enc = -(sum+1) -> MSB=1, <= -1.0); the
//     last block spin-validates all 2048 entries and writes the scalar.
//     Poison 0xAAAAAAAA (-3e-13) and zeroed memory both fail validation;
//     no memset, no grid.sync, no same-address atomics.

#define FK_B   262144
#define NBLK1  (FK_B / 512)        // 512 blocks, 256 thr, 2 elem/thread
#define NPART  (NBLK1 * 4)         // per-wave partials: 2048

// Branchless atan2, Cephes-style. Max error ~1e-7 rad.
__device__ __forceinline__ float fast_atan2f(float y, float x) {
    const float ax = fabsf(x), ay = fabsf(y);
    const float mx = fmaxf(ax, ay);
    const float mn = fminf(ax, ay);
    float t = __fdividef(mn, fmaxf(mx, 1e-30f));
    const bool red = t > 0.41421356f;                  // tan(pi/8)
    const float tr = __fdividef(t - 1.0f, t + 1.0f);
    float u = red ? tr : t;
    const float s = u * u;
    float p = fmaf(s, 8.05374449538e-2f, -1.38776856032e-1f);
    p = fmaf(s, p, 1.99777106478e-1f);
    p = fmaf(s, p, -3.33329491539e-1f);
    float r = fmaf(u * s, p, u);
    if (red) r += 0.78539816340f;
    if (ay > ax) r = 1.57079632679f - r;
    if (x < 0.0f) r = 3.14159265359f - r;
    return copysignf(r, y);
}

// T <- T * A(ct, st, d, a, cal, sal); bottom row [0,0,0,1].
__device__ __forceinline__ void dh_step(float R[3][3], float p[3],
                                        float ct, float st,
                                        float d, float a,
                                        float cal, float sal) {
    const float c0x = ct,        c0y = st,        c0z = 0.0f;
    const float c1x = -st * cal, c1y = ct * cal,  c1z = sal;
    const float c2x = st * sal,  c2y = -ct * sal, c2z = cal;
    const float px = a * ct, py = a * st, pz = d;

    float nR[3][3], np[3];
#pragma unroll
    for (int r = 0; r < 3; ++r) {
        nR[r][0] = R[r][0] * c0x + R[r][1] * c0y + R[r][2] * c0z;
        nR[r][1] = R[r][0] * c1x + R[r][1] * c1y + R[r][2] * c1z;
        nR[r][2] = R[r][0] * c2x + R[r][1] * c2y + R[r][2] * c2z;
        np[r]    = R[r][0] * px  + R[r][1] * py  + R[r][2] * pz + p[r];
    }
#pragma unroll
    for (int r = 0; r < 3; ++r) {
        R[r][0] = nR[r][0]; R[r][1] = nR[r][1]; R[r][2] = nR[r][2];
        p[r] = np[r];
    }
}

// One element's FK + squared error against its pose row (6 floats).
__device__ __forceinline__ float fk_err(const float* q7, const float* pose6) {
    float s[7], c[7];
#pragma unroll
    for (int k = 0; k < 7; ++k) {
        s[k] = __sinf(q7[k]);   // |q| ~ N(0,1): HW trig fully accurate
        c[k] = __cosf(q7[k]);
    }

    float R[3][3] = {{c[0], -s[0], 0.0f},
                     {s[0],  c[0], 0.0f},
                     {0.0f,  0.0f, 1.0f}};
    float p[3] = {0.0f, 0.0f, 0.333f};

    //            ct    st     d       a        cal   sal
    dh_step(R, p, c[1], s[1], 0.0f,   0.0f,    0.0f, -1.0f);
    dh_step(R, p, c[2], s[2], 0.316f, 0.0f,    0.0f,  1.0f);
    dh_step(R, p, c[3], s[3], 0.0f,   0.0825f, 0.0f,  1.0f);
    dh_step(R, p, c[4], s[4], 0.384f,-0.0825f, 0.0f, -1.0f);
    dh_step(R, p, c[5], s[5], 0.0f,   0.0f,    0.0f,  1.0f);
    dh_step(R, p, c[6], s[6], 0.107f, 0.088f,  0.0f,  1.0f);

    float fk[6];
    fk[0] = p[0]; fk[1] = p[1]; fk[2] = p[2];
    fk[3] = fast_atan2f(-R[1][2], R[2][2]);
    const float r02 = fminf(1.0f, fmaxf(-1.0f, R[0][2]));
    fk[4] = fast_atan2f(r02, sqrtf(fmaxf(0.0f, 1.0f - r02 * r02)));
    fk[5] = fast_atan2f(-R[0][1], R[0][0]);

    float err = 0.0f;
#pragma unroll
    for (int k = 0; k < 6; ++k) {
        const float d6 = fk[k] - pose6[k];
        err = fmaf(d6, d6, err);
    }
    return err;
}

__global__ __launch_bounds__(256, 2) void fk_loss_fused(
    const float* __restrict__ joints,   // (B,7)
    const float* __restrict__ poses,    // (B,6)
    float* __restrict__ partials,       // (NPART,) in d_ws
    float* __restrict__ out)            // scalar
{
    const int t   = threadIdx.x;
    const int bid = blockIdx.x;
    const int g   = bid * 256 + t;      // handles elements 2g, 2g+1
    const int lane = t & 63;

    // Dense aligned float2 loads: 14 joint floats + 12 pose floats.
    const float2* jg = (const float2*)joints + g * 7;
    const float2* pg = (const float2*)poses  + g * 6;

    float jq[14], pq[12];
#pragma unroll
    for (int k = 0; k < 7; ++k) {
        const float2 v = jg[k];
        jq[2 * k] = v.x; jq[2 * k + 1] = v.y;
    }
#pragma unroll
    for (int k = 0; k < 6; ++k) {
        const float2 v = pg[k];
        pq[2 * k] = v.x; pq[2 * k + 1] = v.y;
    }

    // Two independent DH chains (ILP-2).
    float err = fk_err(&jq[0], &pq[0]) + fk_err(&jq[7], &pq[6]);

    // wave-64 reduction
#pragma unroll
    for (int off = 32; off > 0; off >>= 1)
        err += __shfl_down(err, off, 64);

    // Per-wave partial, sentinel-encoded: enc = -(sum+1) -> always <= -1.0f.
    // Poison 0xAAAAAAAA (= -3.0e-13) and zeros both FAIL the validity test.
    unsigned int* pu = (unsigned int*)partials;
    if (lane == 0) {
        const float enc = -(err + 1.0f);
        __hip_atomic_store(&pu[g >> 6], __float_as_uint(enc),
                           __ATOMIC_RELAXED, __HIP_MEMORY_SCOPE_AGENT);
    }

    // ---- Last block reduces all NPART partials ----
    if (bid == NBLK1 - 1) {
        float acc = 0.0f;
#pragma unroll
        for (int k = 0; k < NPART / 256; ++k) {
            const int idx = t + k * 256;
            unsigned int bits = __hip_atomic_load(&pu[idx], __ATOMIC_RELAXED,
                                                  __HIP_MEMORY_SCOPE_AGENT);
            while (!((bits & 0x80000000u) && bits != 0xAAAAAAAAu)) {
                __builtin_amdgcn_s_sleep(1);
                bits = __hip_atomic_load(&pu[idx], __ATOMIC_RELAXED,
                                         __HIP_MEMORY_SCOPE_AGENT);
            }
            acc += (-__uint_as_float(bits)) - 1.0f;   // decode
        }

#pragma unroll
        for (int off = 32; off > 0; off >>= 1)
            acc += __shfl_down(acc, off, 64);

        __shared__ float wsum[4];
        if (lane == 0) wsum[t >> 6] = acc;
        __syncthreads();
        if (t == 0)
            out[0] = (wsum[0] + wsum[1] + wsum[2] + wsum[3])
                     * (1.0f / (FK_B * 6.0f));
    }
}

extern "C" void kernel_launch(void* const* d_in, const int* in_sizes, int n_in,
                              void* d_out, int out_size, void* d_ws, size_t ws_size,
                              hipStream_t stream) {
    const float* joints = (const float*)d_in[0];
    const float* poses  = (const float*)d_in[1];
    float* out      = (float*)d_out;
    float* partials = (float*)d_ws;   // poisoned 0xAA each iter; validated

    fk_loss_fused<<<NBLK1, 256, 0, stream>>>(joints, poses, partials, out);
}